// Round 7
// baseline (2148.491 us; speedup 1.0000x reference)
//
#include <hip/hip_runtime.h>
#include <stdint.h>

// CfC RNN: B=256, T=1024, I=64, U=256, O=64, BB=128. All I/O float32.
// MFMA redesign: one WG (1024 thr, 16 waves) per batch row. Inner products
// via v_mfma_f32_16x16x32_f16 with M=1: A = broadcast activation vector
// (all rows identical -> C replicated, no cross-lane reduce), B = weight
// fragments resident in VGPR/AGPR (MFMA reads AGPR directly -> the
// allocator's AGPR parking of weights becomes FREE, unlike v_dot2 which
// paid v_accvgpr_read per use -- R5/R6 evidence: VGPR_Count=64 pinned).
// Readout GEMM deferred via f16-pair H buffer in d_ws (ro_kernel, verified).
// Fallback (ws too small): R6 dot2 kernel with in-loop readout.
#define B_ 256
#define T_ 1024
#define I_ 64
#define U_ 256
#define O_ 64
#define BB_ 128

typedef unsigned int u32;
typedef unsigned short u16;
typedef _Float16 f16;
typedef _Float16 f16x8 __attribute__((ext_vector_type(8)));
typedef float f32x4 __attribute__((ext_vector_type(4)));
typedef _Float16 half2_t __attribute__((ext_vector_type(2)));

#if defined(__has_builtin)
#if __has_builtin(__builtin_amdgcn_fdot2)
#define USE_DOT2 1
#else
#define USE_DOT2 0
#endif
#else
#define USE_DOT2 0
#endif

static __device__ __forceinline__ u32 packpair(float a, float b) {
  half2_t h; h.x = (f16)a; h.y = (f16)b;
  return __builtin_bit_cast(u32, h);
}
static __device__ __forceinline__ float unpack_lo(u32 u) {
  half2_t h = __builtin_bit_cast(half2_t, u); return (float)h.x;
}
static __device__ __forceinline__ float unpack_hi(u32 u) {
  half2_t h = __builtin_bit_cast(half2_t, u); return (float)h.y;
}
static __device__ __forceinline__ float dot2acc(u32 w, u32 z, float acc) {
#if USE_DOT2
  return __builtin_amdgcn_fdot2(__builtin_bit_cast(half2_t, w),
                                __builtin_bit_cast(half2_t, z), acc, false);
#else
  half2_t hw = __builtin_bit_cast(half2_t, w);
  half2_t hz = __builtin_bit_cast(half2_t, z);
  acc += (float)hw.x * (float)hz.x;
  acc += (float)hw.y * (float)hz.y;
  return acc;
#endif
}

// palindromic DPP (self-inverse controls only)
template <int CTRL>
static __device__ __forceinline__ float dpp_mov_f(float v) {
  return __builtin_bit_cast(float, __builtin_amdgcn_update_dpp(
      0, __builtin_bit_cast(int, v), CTRL, 0xF, 0xF, true));
}
#define DPP_XOR1 0xB1
#define DPP_XOR2 0x4E
#define DPP_HMIR 0x141
#define DPP_MIRR 0x140

// NaN-free saturating tanh/sigmoid (exp overflow -> inf -> correct limit)
static __device__ __forceinline__ float fast_tanh(float x) {
  return 1.0f - 2.0f / (1.0f + __expf(2.0f * x));
}
static __device__ __forceinline__ float fast_sigmoid(float x) {
  return 1.0f / (1.0f + __expf(-x));
}

// ============================ MFMA main kernel ============================
// Fragment layouts (gfx950 16x16x32 f16, m89/m91/m120-verified family):
//   A: lane L supplies A[m = L&15][k = (L>>4)*8 + j], j=0..7
//   B: lane L supplies B[k = (L>>4)*8 + j][n = L&15]   (mirror of A)
//   C/D: lane L reg r holds D[row = (L>>4)*4 + r][col = L&15]
// M=1 trick: feed A-frag = same 8 f16 on every lane (broadcast z slice) ->
// all 16 A-rows identical -> D rows identical -> any lane/reg0 is the answer
// for its column. No reduce needed.
__global__ __launch_bounds__(1024, 4)
void cfc_mfma_kernel(const float* __restrict__ x,
                     const float* __restrict__ W_bb, const float* __restrict__ b_bb,
                     const float* __restrict__ W_ff1, const float* __restrict__ b_ff1,
                     const float* __restrict__ W_ff2, const float* __restrict__ b_ff2,
                     const float* __restrict__ W_ta,  const float* __restrict__ b_ta,
                     const float* __restrict__ W_tb,  const float* __restrict__ b_tb,
                     float* __restrict__ out, u32* __restrict__ Hbuf)
{
  __shared__ __align__(16) f16   s_x[2][64];    // x_t ping-pong (A-ready vector)
  __shared__ __align__(16) f16   s_h[256];      // h_t (A-ready vector)
  __shared__ __align__(16) f16   s_g[128];      // g_t (A-ready vector)
  __shared__ __align__(16) float s_red[16][16]; // backbone K-half partials

  const int tid = threadIdx.x;
  const int w   = tid >> 6;   // wave 0..15
  const int L   = tid & 63;
  const int l15 = L & 15;
  const int q   = L >> 4;
  const int r   = blockIdx.x;

  // ---- backbone B-frags: wave = (tile an = w>>1, K-half as = w&1) ----
  const int an = w >> 1;
  const int as = w & 1;
  f16x8 wbb[5];
  for (int i = 0; i < 5; ++i) {
    int kt = 5 * as + i;
    f16x8 f;
#pragma unroll
    for (int j = 0; j < 8; ++j)
      f[j] = (f16)W_bb[(32 * kt + 8 * q + j) * BB_ + 16 * an + l15];
    wbb[i] = f;
  }
  // ---- ff B-frags: wave w owns unit range 16w..16w+15 of all 4 mats ----
  const int u = 16 * w + l15;
  const float* Wm[4] = {W_ff1, W_ff2, W_ta, W_tb};
  f16x8 wf[4][4];  // [mat][kt]
  for (int m = 0; m < 4; ++m)
    for (int kt = 0; kt < 4; ++kt) {
      f16x8 f;
#pragma unroll
      for (int j = 0; j < 8; ++j)
        f[j] = (f16)Wm[m][(32 * kt + 8 * q + j) * U_ + u];
      wf[m][kt] = f;
    }
  const float b1 = b_ff1[u], b2 = b_ff2[u];
  const float bta = b_ta[u], btb = b_tb[u];
  float bbbn = 0.f;
  if (w < 8) bbbn = b_bb[16 * w + l15];  // g-finalize: wave w' owns tile w'

  const float* xrow = x + (size_t)r * T_ * I_;
  u32* __restrict__ hrow = Hbuf + (size_t)r * T_ * 128;

  // ---- init: h0 = 0, stage x_0 into slot 0 ----
  if (tid < 128) ((u32*)s_h)[tid] = 0u;
  if (tid < 32) {
    float2 xv = ((const float2*)xrow)[tid];
    half2_t p; p.x = (f16)xv.x; p.y = (f16)xv.y;
    ((half2_t*)s_x[0])[tid] = p;
  }
  __syncthreads();

  for (int t = 0; t < T_; ++t) {
    // =============== Phase A: backbone (K-split 2) + side duties ===========
    const f16* xslot = s_x[t & 1];
    f32x4 ca = {0.f, 0.f, 0.f, 0.f};
#pragma unroll
    for (int i = 0; i < 5; ++i) {
      int kt = 5 * as + i;
      const f16* ap = (kt < 2) ? (xslot + 32 * kt + 8 * q)
                               : (s_h + 32 * (kt - 2) + 8 * q);
      f16x8 af = *(const f16x8*)ap;   // 16-lane broadcast b128
      ca = __builtin_amdgcn_mfma_f32_16x16x32_f16(af, wbb[i], ca, 0, 0, 0);
    }
    if (L < 16) s_red[w][l15] = ca[0];
    // side duties in phase A's shadow (uniform wave branches):
    if (w == 8 || w == 9) {          // stream h_{t-1} -> Hbuf
      if (t > 0) {
        int idx = (w - 8) * 64 + L;
        hrow[(size_t)(t - 1) * 128 + idx] = ((const u32*)s_h)[idx];
      }
    } else if (w == 10) {            // stage x_{t+1} into the other slot
      if (t + 1 < T_ && L < 32) {
        float2 xv = ((const float2*)(xrow + (size_t)(t + 1) * I_))[L];
        half2_t p; p.x = (f16)xv.x; p.y = (f16)xv.y;
        ((half2_t*)s_x[(t + 1) & 1])[L] = p;
      }
    }
    __syncthreads();  // b1: partials ready

    if (w < 8 && L < 16) {
      float pre = s_red[2 * w][l15] + s_red[2 * w + 1][l15] + bbbn;
      s_g[16 * w + l15] = (f16)(1.7159f * fast_tanh(0.666f * pre));
    }
    __syncthreads();  // b2: g ready

    // =============== Phase B: fused ff1/ff2/ta/tb + gates ==================
    f32x4 c0 = {0,0,0,0}, c1 = {0,0,0,0}, c2 = {0,0,0,0}, c3 = {0,0,0,0};
#pragma unroll
    for (int kt = 0; kt < 4; ++kt) {
      f16x8 gf = *(const f16x8*)(s_g + 32 * kt + 8 * q);
      c0 = __builtin_amdgcn_mfma_f32_16x16x32_f16(gf, wf[0][kt], c0, 0, 0, 0);
      c1 = __builtin_amdgcn_mfma_f32_16x16x32_f16(gf, wf[1][kt], c1, 0, 0, 0);
      c2 = __builtin_amdgcn_mfma_f32_16x16x32_f16(gf, wf[2][kt], c2, 0, 0, 0);
      c3 = __builtin_amdgcn_mfma_f32_16x16x32_f16(gf, wf[3][kt], c3, 0, 0, 0);
    }
    float f1 = fast_tanh(c0[0] + b1);
    float f2 = fast_tanh(c1[0] + b2);
    float ti = fast_sigmoid(c2[0] + bta + c3[0] + btb);
    float h  = f1 + ti * (f2 - f1);
    float hx = dpp_mov_f<DPP_XOR1>(h);   // partner unit u^1 (palindromic)
    if (L < 16 && !(L & 1)) {
      half2_t p; p.x = (f16)h; p.y = (f16)hx;
      ((half2_t*)s_h)[8 * w + (l15 >> 1)] = p;  // units (16w+l15, +1)
    }
    __syncthreads();  // b0: h_t ready for next step
  }

  // ---- epilogue: Hbuf[T-1] + h_last -> d_out tail ----
  if (tid < 128) {
    u32 hp = ((const u32*)s_h)[tid];
    hrow[(size_t)(T_ - 1) * 128 + tid] = hp;
    float2 hv; hv.x = unpack_lo(hp); hv.y = unpack_hi(hp);
    ((float2*)(out + (size_t)B_ * T_ * O_))[r * 128 + tid] = hv;
  }
}

// Deferred readout: out[r,t,:] = H[r,t,:] @ W_fc + b_fc.  (verified R5/R6)
__global__ __launch_bounds__(512)
void ro_kernel(const u32* __restrict__ Hbuf,
               const float* __restrict__ W_fc, const float* __restrict__ b_fc,
               float* __restrict__ out)
{
  __shared__ __align__(16) u32 s_hb[8 * 128];
  const int tid = threadIdx.x;
  const int o   = tid & 63;
  const int w   = tid >> 6;
  const int r   = blockIdx.x;

  u32 wfc[128];
#pragma unroll
  for (int p = 0; p < 128; ++p)
    wfc[p] = packpair(W_fc[(2 * p) * O_ + o], W_fc[(2 * p + 1) * O_ + o]);
  const float bo = b_fc[o];

  const u32* hrow = Hbuf + (size_t)r * T_ * 128;
  const size_t out_row = (size_t)r * T_ * O_;

  for (int c = 0; c < T_ / 8; ++c) {
    *(uint2*)(s_hb + 2 * tid) =
        *(const uint2*)(hrow + (size_t)c * 1024 + 2 * tid);
    __syncthreads();
    float acc = bo;
    const uint4* h4 = reinterpret_cast<const uint4*>(s_hb + w * 128);
#pragma unroll
    for (int i = 0; i < 32; ++i) {
      uint4 hh = h4[i];
      acc = dot2acc(wfc[4 * i + 0], hh.x, acc);
      acc = dot2acc(wfc[4 * i + 1], hh.y, acc);
      acc = dot2acc(wfc[4 * i + 2], hh.z, acc);
      acc = dot2acc(wfc[4 * i + 3], hh.w, acc);
    }
    out[out_row + (size_t)(8 * c + w) * O_ + o] = acc;
    __syncthreads();
  }
}

// ================= fallback (ws too small): R6 dot2 kernel ================
__global__ __launch_bounds__(1024)
void cfc_dot2_kernel(const float* __restrict__ x,
                const float* __restrict__ W_bb, const float* __restrict__ b_bb,
                const float* __restrict__ W_ff1, const float* __restrict__ b_ff1,
                const float* __restrict__ W_ff2, const float* __restrict__ b_ff2,
                const float* __restrict__ W_ta,  const float* __restrict__ b_ta,
                const float* __restrict__ W_tb,  const float* __restrict__ b_tb,
                const float* __restrict__ W_fc,  const float* __restrict__ b_fc,
                float* __restrict__ out)
{
  __shared__ __align__(16) u32 s_z2[160];
  __shared__ __align__(16) u32 s_g2[64];
  u16* s_gh = (u16*)s_g2;

  const int tid = threadIdx.x;
  const int r   = blockIdx.x;
  const int ca  = tid >> 3;
  const int kga = tid & 7;
  const int jb = tid >> 2;
  const int kq = tid & 3;
  const int ro = tid >> 4;
  const int rk = tid & 15;

  u32 wbb[20];
#pragma unroll
  for (int j = 0; j < 5; ++j)
#pragma unroll
    for (int qq = 0; qq < 4; ++qq) {
      int p = 4 * (kga + 8 * j) + qq;
      wbb[4 * j + qq] = packpair(W_bb[(2 * p) * BB_ + ca],
                                 W_bb[(2 * p + 1) * BB_ + ca]);
    }
  u32 wf1[16], wf2[16], wta[16], wtb[16];
#pragma unroll
  for (int j = 0; j < 4; ++j)
#pragma unroll
    for (int qq = 0; qq < 4; ++qq) {
      int p = 4 * (kq + 4 * j) + qq;
      int k0 = 2 * p, k1 = 2 * p + 1;
      wf1[4 * j + qq] = packpair(W_ff1[k0 * U_ + jb], W_ff1[k1 * U_ + jb]);
      wf2[4 * j + qq] = packpair(W_ff2[k0 * U_ + jb], W_ff2[k1 * U_ + jb]);
      wta[4 * j + qq] = packpair(W_ta [k0 * U_ + jb], W_ta [k1 * U_ + jb]);
      wtb[4 * j + qq] = packpair(W_tb [k0 * U_ + jb], W_tb [k1 * U_ + jb]);
    }
  u32 wfc[8];
#pragma unroll
  for (int j = 0; j < 2; ++j)
#pragma unroll
    for (int qq = 0; qq < 4; ++qq) {
      int p = 4 * (rk + 16 * j) + qq;
      wfc[4 * j + qq] = packpair(W_fc[(2 * p) * O_ + ro],
                                 W_fc[(2 * p + 1) * O_ + ro]);
    }
  const float bfo = b_fc[ro];
  const float bbbc = b_bb[ca];
  const float b1 = b_ff1[jb], b2 = b_ff2[jb];
  const float bta = b_ta[jb], btb = b_tb[jb];

  const float* xrow = x + (size_t)r * T_ * I_;
  const size_t out_row = (size_t)r * T_ * O_;

  if (tid < 160) s_z2[tid] = 0u;
  __syncthreads();
  if (tid < 32) {
    float2 xv = ((const float2*)xrow)[tid];
    s_z2[tid] = packpair(xv.x, xv.y);
  }
  __syncthreads();

  for (int t = 0; t < T_; ++t) {
    float2 xv;
    const bool ldx = (tid < 32) && (t + 1 < T_);
    if (ldx) xv = ((const float2*)(xrow + (size_t)(t + 1) * I_))[tid];

    float bacc = 0.f;
#pragma unroll
    for (int j = 0; j < 5; ++j) {
      uint4 zz = *reinterpret_cast<const uint4*>(s_z2 + 4 * (kga + 8 * j));
      bacc = dot2acc(wbb[4 * j + 0], zz.x, bacc);
      bacc = dot2acc(wbb[4 * j + 1], zz.y, bacc);
      bacc = dot2acc(wbb[4 * j + 2], zz.z, bacc);
      bacc = dot2acc(wbb[4 * j + 3], zz.w, bacc);
    }
    bacc += dpp_mov_f<DPP_XOR1>(bacc);
    bacc += dpp_mov_f<DPP_XOR2>(bacc);
    bacc += dpp_mov_f<DPP_HMIR>(bacc);
    float g = 1.7159f * fast_tanh(0.666f * (bacc + bbbc));

    float racc = 0.f;
#pragma unroll
    for (int j = 0; j < 2; ++j) {
      uint4 hh = *reinterpret_cast<const uint4*>(s_z2 + 32 + 4 * (rk + 16 * j));
      racc = dot2acc(wfc[4 * j + 0], hh.x, racc);
      racc = dot2acc(wfc[4 * j + 1], hh.y, racc);
      racc = dot2acc(wfc[4 * j + 2], hh.z, racc);
      racc = dot2acc(wfc[4 * j + 3], hh.w, racc);
    }
    racc += dpp_mov_f<DPP_XOR1>(racc);
    racc += dpp_mov_f<DPP_XOR2>(racc);
    racc += dpp_mov_f<DPP_HMIR>(racc);
    racc += dpp_mov_f<DPP_MIRR>(racc);

    if ((tid & 7) == 0)
      s_gh[ca] = __builtin_bit_cast(u16, (f16)g);
    if (t > 0 && rk == 0)
      out[out_row + (size_t)(t - 1) * O_ + ro] = racc + bfo;
    __syncthreads();

    float a1 = 0.f, a2 = 0.f, a3 = 0.f, a4 = 0.f;
#pragma unroll
    for (int j = 0; j < 4; ++j) {
      uint4 gg = *reinterpret_cast<const uint4*>(s_g2 + 4 * (kq + 4 * j));
      a1 = dot2acc(wf1[4 * j + 0], gg.x, a1);
      a1 = dot2acc(wf1[4 * j + 1], gg.y, a1);
      a1 = dot2acc(wf1[4 * j + 2], gg.z, a1);
      a1 = dot2acc(wf1[4 * j + 3], gg.w, a1);
      a2 = dot2acc(wf2[4 * j + 0], gg.x, a2);
      a2 = dot2acc(wf2[4 * j + 1], gg.y, a2);
      a2 = dot2acc(wf2[4 * j + 2], gg.z, a2);
      a2 = dot2acc(wf2[4 * j + 3], gg.w, a2);
      a3 = dot2acc(wta[4 * j + 0], gg.x, a3);
      a3 = dot2acc(wta[4 * j + 1], gg.y, a3);
      a3 = dot2acc(wta[4 * j + 2], gg.z, a3);
      a3 = dot2acc(wta[4 * j + 3], gg.w, a3);
      a4 = dot2acc(wtb[4 * j + 0], gg.x, a4);
      a4 = dot2acc(wtb[4 * j + 1], gg.y, a4);
      a4 = dot2acc(wtb[4 * j + 2], gg.z, a4);
      a4 = dot2acc(wtb[4 * j + 3], gg.w, a4);
    }
    a1 += dpp_mov_f<DPP_XOR1>(a1); a1 += dpp_mov_f<DPP_XOR2>(a1);
    a2 += dpp_mov_f<DPP_XOR1>(a2); a2 += dpp_mov_f<DPP_XOR2>(a2);
    a3 += dpp_mov_f<DPP_XOR1>(a3); a3 += dpp_mov_f<DPP_XOR2>(a3);
    a4 += dpp_mov_f<DPP_XOR1>(a4); a4 += dpp_mov_f<DPP_XOR2>(a4);
    float f1 = fast_tanh(a1 + b1);
    float f2 = fast_tanh(a2 + b2);
    float ti = fast_sigmoid(a3 + bta + a4 + btb);
    float h  = f1 + ti * (f2 - f1);
    float hq = dpp_mov_f<DPP_HMIR>(h);

    if ((tid & 7) == 0)
      s_z2[32 + (tid >> 3)] = packpair(h, hq);
    if (ldx) s_z2[tid] = packpair(xv.x, xv.y);
    __syncthreads();
  }

  {
    float racc = 0.f;
#pragma unroll
    for (int j = 0; j < 2; ++j) {
      uint4 hh = *reinterpret_cast<const uint4*>(s_z2 + 32 + 4 * (rk + 16 * j));
      racc = dot2acc(wfc[4 * j + 0], hh.x, racc);
      racc = dot2acc(wfc[4 * j + 1], hh.y, racc);
      racc = dot2acc(wfc[4 * j + 2], hh.z, racc);
      racc = dot2acc(wfc[4 * j + 3], hh.w, racc);
    }
    racc += dpp_mov_f<DPP_XOR1>(racc);
    racc += dpp_mov_f<DPP_XOR2>(racc);
    racc += dpp_mov_f<DPP_HMIR>(racc);
    racc += dpp_mov_f<DPP_MIRR>(racc);
    if (rk == 0)
      out[out_row + (size_t)(T_ - 1) * O_ + ro] = racc + bfo;
  }

  if (tid < 128) {
    u32 hp = s_z2[32 + tid];
    float2 hv; hv.x = unpack_lo(hp); hv.y = unpack_hi(hp);
    ((float2*)(out + (size_t)B_ * T_ * O_))[r * 128 + tid] = hv;
  }
}

extern "C" void kernel_launch(void* const* d_in, const int* in_sizes, int n_in,
                              void* d_out, int out_size, void* d_ws, size_t ws_size,
                              hipStream_t stream) {
  const float* x     = (const float*)d_in[0];
  const float* W_bb  = (const float*)d_in[1];
  const float* b_bb  = (const float*)d_in[2];
  const float* W_ff1 = (const float*)d_in[3];
  const float* b_ff1 = (const float*)d_in[4];
  const float* W_ff2 = (const float*)d_in[5];
  const float* b_ff2 = (const float*)d_in[6];
  const float* W_ta  = (const float*)d_in[7];
  const float* b_ta  = (const float*)d_in[8];
  const float* W_tb  = (const float*)d_in[9];
  const float* b_tb  = (const float*)d_in[10];
  const float* W_fc  = (const float*)d_in[11];
  const float* b_fc  = (const float*)d_in[12];
  float* out = (float*)d_out;

  const size_t h_bytes = (size_t)B_ * T_ * 128 * sizeof(u32);  // 128 MiB
  if (ws_size >= h_bytes) {
    u32* Hbuf = (u32*)d_ws;
    cfc_mfma_kernel<<<dim3(B_), dim3(1024), 0, stream>>>(
        x, W_bb, b_bb, W_ff1, b_ff1, W_ff2, b_ff2,
        W_ta, b_ta, W_tb, b_tb, out, Hbuf);
    ro_kernel<<<dim3(B_), dim3(512), 0, stream>>>(Hbuf, W_fc, b_fc, out);
  } else {
    cfc_dot2_kernel<<<dim3(B_), dim3(1024), 0, stream>>>(
        x, W_bb, b_bb, W_ff1, b_ff1, W_ff2, b_ff2,
        W_ta, b_ta, W_tb, b_tb, W_fc, b_fc, out);
  }
}